// Round 9
// baseline (253.190 us; speedup 1.0000x reference)
//
#include <hip/hip_runtime.h>
#include <hip/hip_bf16.h>

typedef unsigned short u16;
typedef __attribute__((ext_vector_type(8))) __bf16 bf16x8;
typedef __attribute__((ext_vector_type(4))) float floatx4;

#define B_   16
#define N1_  4096
#define N2_  1024
#define C1_  128
#define C2_  256
#define CIN_ 384
#define CM_  256
#define CO_  128

__device__ __forceinline__ u16 f2bf(float f) {
  unsigned u = __float_as_uint(f);
  u = (u + 0x7fffu + ((u >> 16) & 1u)) >> 16;
  return (u16)u;
}
__device__ __forceinline__ float bf2f(u16 h) {
  return __uint_as_float(((unsigned)h) << 16);
}

union U128 { uint4 u; bf16x8 v; u16 s[8]; };

__device__ __forceinline__ bf16x8 ldfrag(const u16* p) {
  U128 x; x.u = *(const uint4*)p; return x.v;
}
__device__ __forceinline__ uint4 pack8(const u16* h) {
  uint4 u;
  u.x = (unsigned)h[0] | ((unsigned)h[1] << 16);
  u.y = (unsigned)h[2] | ((unsigned)h[3] << 16);
  u.z = (unsigned)h[4] | ((unsigned)h[5] << 16);
  u.w = (unsigned)h[6] | ((unsigned)h[7] << 16);
  return u;
}

// Tiled operand layout (MFMA-fragment-major):
//   frag(tile, kt) at [tile][kt][lane][8] u16, lane = quad*16+col,
//   element j = M[row=col][k = kt*32 + quad*8 + j]. Wave frag load = base + lane*16B.
// GEMM lesson (R5-R7): global_load_lds deep rings stall the LDS-DMA queue; register
// staging period-3 with compiler-counted vmcnt is the proven form (R7: gemm1 < knn).
// KNN lesson (R8): small chunks reset top-3 thresholds -> insert chain fires ~0.9/iter;
// chunk=512 cuts fire-rate to ~0.6 (chain is ~13 of ~23 slots/iter).

// ---------------- K1 MEGA: independent front-end work co-scheduled ----------------
// grid 1920 x 256:
//   id <  512  : knn 3-NN partials, chunk=512 (dispatched FIRST: the long pole)
//   id <  640  : weight cast (w0,w1 -> fragment-major bf16)
//   id <  896  : feat2 transpose -> feat2Tb[b][n2][c] bf16 (2 half-passes, 33KB LDS)
//   else       : feat1 transpose -> xcatT kt 0..3
__global__ __launch_bounds__(256) void mega_kernel(
    const float* __restrict__ xyz1, const float* __restrict__ xyz2,
    float* __restrict__ pd, int* __restrict__ pi,
    const float* __restrict__ w0, const float* __restrict__ w1,
    u16* __restrict__ w0b, u16* __restrict__ w1b,
    const float* __restrict__ feat2, u16* __restrict__ feat2Tb,
    const float* __restrict__ feat1, u16* __restrict__ xcatT)
{
  __shared__ __align__(16) float smem[64*133];     // 34,048 B, aliased per branch
  int t = threadIdx.x;
  int id = blockIdx.x;
  if (id < 512) {
    // ---- knn: one point/thread, 512 candidates (branchy insert: measured best) ----
    float4* sp = (float4*)smem;                    // 512 x 16B = 8KB
    int xb = id & 15, b = (id >> 4) & 15, chunk = id >> 8;
    const float* p2 = xyz2 + ((size_t)b * N2_ + chunk * 512) * 3;
    #pragma unroll
    for (int l = t; l < 512; l += 256)
      sp[l] = make_float4(p2[l*3], p2[l*3+1], p2[l*3+2], 0.f);
    __syncthreads();
    int i = xb * 256 + t;
    const float* p1 = xyz1 + ((size_t)b * N1_ + i) * 3;
    float x = p1[0], y = p1[1], z = p1[2];
    float d0 = 1e30f, d1 = 1e30f, d2 = 1e30f;
    int i0 = 0, i1 = 0, i2 = 0;
    int jb = chunk * 512;
    #pragma unroll 4
    for (int j = 0; j < 512; ++j) {
      float4 p = sp[j];                            // broadcast: conflict-free
      float dx = x - p.x, dy = y - p.y, dz = z - p.z;
      float d = dx*dx + dy*dy + dz*dz;
      if (d < d2) {                                // strict <: stable (earlier j wins ties)
        int jj = jb + j;
        if (d < d0)      { d2=d1; i2=i1; d1=d0; i1=i0; d0=d; i0=jj; }
        else if (d < d1) { d2=d1; i2=i1; d1=d;  i1=jj; }
        else             { d2=d;  i2=jj; }
      }
    }
    int o = chunk*65536 + b*4096 + i;
    pd[o] = d0; pd[o + 131072] = d1; pd[o + 262144] = d2;
    pi[o] = i0; pi[o + 131072] = i1; pi[o + 262144] = i2;
    return;
  }
  if (id < 640) {                                  // ---- castw ----
    int item = (id - 512) * 256 + t;               // 0..32767
    if (item < 12288) {                            // w0: 256 rows x 48 chunks
      int m = item / 48, kc = item % 48;
      const float* p = w0 + m * CIN_ + kc * 8;
      u16 h8[8];
      #pragma unroll
      for (int j = 0; j < 8; ++j) h8[j] = f2bf(p[j]);
      int mt = m >> 4, col = m & 15, kt = kc >> 2, quad = kc & 3;
      *(uint4*)(w0b + ((mt*12 + kt)*512 + (quad*16 + col)*8)) = pack8(h8);
    } else if (item < 16384) {                     // w1: 128 rows x 32 chunks
      int i2 = item - 12288;
      int m = i2 >> 5, kc = i2 & 31;
      const float* p = w1 + m * CM_ + kc * 8;
      u16 h8[8];
      #pragma unroll
      for (int j = 0; j < 8; ++j) h8[j] = f2bf(p[j]);
      int mt = m >> 4, col = m & 15, kt = kc >> 2, quad = kc & 3;
      *(uint4*)(w1b + ((mt*8 + kt)*512 + (quad*16 + col)*8)) = pack8(h8);
    }
    return;
  }
  if (id < 896) {
    // ---- feat2 transpose, 2 half-passes of 128 channels (fits 33KB LDS) ----
    float (*sA2)[129] = (float(*)[129])smem;
    int idx = id - 640;
    int b = idx >> 4, n0 = (idx & 15) * 64;
    #pragma unroll 1
    for (int h = 0; h < 2; ++h) {
      if (h) __syncthreads();                      // protect sA2 reuse
      #pragma unroll
      for (int j = 0; j < 8; ++j) {
        int flat4 = t + j * 256;                   // 2048 float4s: 128c x 64n
        int cl = flat4 >> 4, nn4 = (flat4 & 15) * 4;
        float4 v = *(const float4*)(feat2 + ((size_t)b*C2_ + h*128 + cl)*N2_ + n0 + nn4);
        sA2[nn4+0][cl] = v.x; sA2[nn4+1][cl] = v.y; sA2[nn4+2][cl] = v.z; sA2[nn4+3][cl] = v.w;
      }
      __syncthreads();
      int nn = t & 63, chunk = t >> 6;             // 4 x 32-channel groups per half
      u16* dst = feat2Tb + ((size_t)b*N2_ + n0 + nn)*C2_ + h*128 + chunk*32;
      #pragma unroll
      for (int g = 0; g < 4; ++g) {
        u16 h8[8];
        #pragma unroll
        for (int j = 0; j < 8; ++j) h8[j] = f2bf(sA2[nn][chunk*32 + g*8 + j]);
        *(uint4*)(dst + g*8) = pack8(h8);
      }
    }
    return;
  }
  {
    // ---- feat1 transpose -> xcatT kt 0..3 ----
    float (*sA1)[133] = (float(*)[133])smem;
    int idx = id - 896;
    int b = idx >> 6, n0 = (idx & 63) * 64;
    #pragma unroll
    for (int j = 0; j < 8; ++j) {
      int flat4 = t + j * 256;                     // 2048 float4s: 128c x 64n
      int c = flat4 >> 4, nn4 = (flat4 & 15) * 4;
      float4 v = *(const float4*)(feat1 + ((size_t)b*C1_ + c)*N1_ + n0 + nn4);
      sA1[nn4+0][c] = v.x; sA1[nn4+1][c] = v.y; sA1[nn4+2][c] = v.z; sA1[nn4+3][c] = v.w;
    }
    __syncthreads();
    int nn = t & 63, chunk = t >> 6;
    int n = n0 + nn, nt = n >> 4, col = n & 15;
    u16* tb = xcatT + ((size_t)b*256 + nt)*12*512;
    #pragma unroll
    for (int g = 0; g < 4; ++g) {
      int c0 = chunk*32 + g*8;
      u16 h8[8];
      #pragma unroll
      for (int j = 0; j < 8; ++j) h8[j] = f2bf(sA1[nn][c0 + j]);
      *(uint4*)(tb + (size_t)chunk*512 + (g*16 + col)*8) = pack8(h8);
    }
  }
}

// ---------------- K2: fused merge(2 chunks) + 3NN interpolate -> xcatT kt 4..11 ----------------
// grid (64,16): block = 64 points. Phase 1: threads 0..63 merge their point's two
// chunk-triples (ascending chunk, strict < : stable) into LDS. Phase 2: gather.
__global__ __launch_bounds__(256) void interp_kernel(
    const u16* __restrict__ feat2Tb,
    const float* __restrict__ pd, const int* __restrict__ pi,
    u16* __restrict__ xcatT)
{
  __shared__ int   sidx[3][64];
  __shared__ float sw[3][64];
  int b = blockIdx.y;
  int t = threadIdx.x;
  int p0 = blockIdx.x * 64;
  if (t < 64) {
    int p = b*4096 + p0 + t;
    float d0 = 1e30f, d1 = 1e30f, d2 = 1e30f;
    int i0 = 0, i1 = 0, i2 = 0;
    #pragma unroll
    for (int c = 0; c < 2; ++c) {
      int o = c*65536 + p;
      #pragma unroll
      for (int k = 0; k < 3; ++k) {
        float d = pd[o + k*131072];
        int ix = pi[o + k*131072];
        bool c2 = d < d2, c1 = d < d1, c0 = d < d0;
        d2 = c1 ? d1 : (c2 ? d  : d2);
        i2 = c1 ? i1 : (c2 ? ix : i2);
        d1 = c0 ? d0 : (c1 ? d  : d1);
        i1 = c0 ? i0 : (c1 ? ix : i1);
        d0 = c0 ? d  : d0;
        i0 = c0 ? ix : i0;
      }
    }
    float w0 = 1.f/(d0+1e-8f), w1 = 1.f/(d1+1e-8f), w2 = 1.f/(d2+1e-8f);
    float inv = 1.f/(w0+w1+w2);
    sidx[0][t] = i0; sidx[1][t] = i1; sidx[2][t] = i2;
    sw[0][t] = w0*inv; sw[1][t] = w1*inv; sw[2][t] = w2*inv;
  }
  __syncthreads();
  int seg = t & 31;                                // 8-channel segment
  int pl  = t >> 5;                                // 8 points per pass
  #pragma unroll 2
  for (int pass = 0; pass < 8; ++pass) {
    int nl = pass*8 + pl;
    int n = p0 + nl;
    int i0 = sidx[0][nl], i1 = sidx[1][nl], i2 = sidx[2][nl];
    float w0 = sw[0][nl], w1 = sw[1][nl], w2 = sw[2][nl];
    const u16* fb = feat2Tb + (size_t)b*N2_*C2_ + seg*8;
    U128 a, c, d;
    a.u = *(const uint4*)(fb + (size_t)i0*C2_);
    c.u = *(const uint4*)(fb + (size_t)i1*C2_);
    d.u = *(const uint4*)(fb + (size_t)i2*C2_);
    u16 h8[8];
    #pragma unroll
    for (int j = 0; j < 8; ++j)
      h8[j] = f2bf(w0*bf2f(a.s[j]) + w1*bf2f(c.s[j]) + w2*bf2f(d.s[j]));
    int nt = n >> 4, col = n & 15;
    int kt = 4 + (seg >> 2), quad = seg & 3;
    *(uint4*)(xcatT + (((size_t)b*256 + nt)*12 + kt)*512 + (quad*16 + col)*8) = pack8(h8);
  }
}

// ---------------- K3: GEMM1 MFMA, register-staged period-3 depth-2 (R7 proven) ----------------
// grid (32,16,2): x = 8-ntile block, y = batch, z = M half. 4 waves (2x2), wave
// tile 64x64. Compiler inserts counted vmcnt before each MM (no drain-to-0).
__global__ __launch_bounds__(256) void gemm1_mfma(
    const u16* __restrict__ xcatT, const u16* __restrict__ w0b,
    const float* __restrict__ b0p, u16* __restrict__ y0T,
    float* __restrict__ p0)
{
  __shared__ float ps[4][64][2];                   // [wave][ch64][sum|sq]
  int t = threadIdx.x;
  int wave = t >> 6, lane = t & 63;
  int col = lane & 15, quad = lane >> 4;
  int wm = wave >> 1, wn = wave & 1;
  int b = blockIdx.y;
  int mtb = blockIdx.z*8 + wm*4;
  int ntb = blockIdx.x*8 + wn*4;

  const u16* ap = w0b + lane*8;
  const u16* bp = xcatT + ((size_t)(b*256 + ntb)*12)*512 + lane*8;

  floatx4 acc[4][4] = {};
  bf16x8 aA[4], aB[4], aC[4], bA[4], bB[4], bC[4];

#define G1_LDA(BUF, KT) { _Pragma("unroll") for (int i = 0; i < 4; ++i) \
    BUF[i] = ldfrag(ap + (size_t)((mtb+i)*12 + (KT))*512); }
#define G1_LDB(BUF, KT) { _Pragma("unroll") for (int i = 0; i < 4; ++i) \
    BUF[i] = ldfrag(bp + (size_t)(i*12 + (KT))*512); }
#define G1_MM(A_, B_) { _Pragma("unroll") for (int mt = 0; mt < 4; ++mt) \
    _Pragma("unroll") for (int nt = 0; nt < 4; ++nt) \
      acc[mt][nt] = __builtin_amdgcn_mfma_f32_16x16x32_bf16(A_[mt], B_[nt], acc[mt][nt], 0, 0, 0); }

  G1_LDA(aA,0);  G1_LDB(bA,0);
  G1_LDA(aB,1);  G1_LDB(bB,1);
  G1_LDA(aC,2);  G1_LDB(bC,2);
  G1_MM(aA,bA);  G1_LDA(aA,3);  G1_LDB(bA,3);
  G1_MM(aB,bB);  G1_LDA(aB,4);  G1_LDB(bB,4);
  G1_MM(aC,bC);  G1_LDA(aC,5);  G1_LDB(bC,5);
  G1_MM(aA,bA);  G1_LDA(aA,6);  G1_LDB(bA,6);
  G1_MM(aB,bB);  G1_LDA(aB,7);  G1_LDB(bB,7);
  G1_MM(aC,bC);  G1_LDA(aC,8);  G1_LDB(bC,8);
  G1_MM(aA,bA);  G1_LDA(aA,9);  G1_LDB(bA,9);
  G1_MM(aB,bB);  G1_LDA(aB,10); G1_LDB(bB,10);
  G1_MM(aC,bC);  G1_LDA(aC,11); G1_LDB(bC,11);
  G1_MM(aA,bA);
  G1_MM(aB,bB);
  G1_MM(aC,bC);

  int m0 = blockIdx.z*128 + wm*64;
  #pragma unroll
  for (int mt = 0; mt < 4; ++mt) {
    float4 bias4 = *(const float4*)(b0p + m0 + mt*16 + quad*4);
    float bia[4] = {bias4.x, bias4.y, bias4.z, bias4.w};
    int kt_out = (m0 >> 5) + (mt >> 1);
    int quad_out = ((mt & 1) << 1) | (quad >> 1);
    int j0 = (quad & 1) * 4;
    float s[4] = {}, q[4] = {};
    #pragma unroll
    for (int nt = 0; nt < 4; ++nt) {
      int nt_g = ntb + nt;
      u16 h[4];
      #pragma unroll
      for (int r = 0; r < 4; ++r) {
        float v = acc[mt][nt][r] + bia[r];
        u16 hh = f2bf(v);
        float vr = bf2f(hh);
        h[r] = hh; s[r] += vr; q[r] += vr*vr;
      }
      *(ushort4*)(y0T + (((size_t)b*256 + nt_g)*8 + kt_out)*512 + (quad_out*16 + col)*8 + j0)
          = make_ushort4(h[0], h[1], h[2], h[3]);
    }
    #pragma unroll
    for (int r = 0; r < 4; ++r) {
      float ss = s[r], qq = q[r];
      #pragma unroll
      for (int msk = 1; msk < 16; msk <<= 1) { ss += __shfl_xor(ss, msk); qq += __shfl_xor(qq, msk); }
      if (col == 0) {
        ps[wave][mt*16 + quad*4 + r][0] = ss;
        ps[wave][mt*16 + quad*4 + r][1] = qq;
      }
    }
  }
  __syncthreads();
  {
    int c = t >> 1, k = t & 1;                     // c in [0,128)
    int wbase = (c >> 6) * 2, ch = c & 63;
    float v = ps[wbase][ch][k] + ps[wbase+1][ch][k];
    size_t l = (size_t)blockIdx.z*512 + blockIdx.y*32 + blockIdx.x;
    p0[l*256 + t] = v;
  }
}

// ---------------- K3.5: finalize stats -> scale/shift per channel ----------------
__global__ __launch_bounds__(256) void stats_kernel(
    const float* __restrict__ p, const float* __restrict__ g,
    const float* __restrict__ be, float* __restrict__ scale,
    float* __restrict__ shift, int half_split, int nl)
{
  int c = blockIdx.x, t = threadIdx.x;
  size_t base = half_split ? ((size_t)(c >> 7) * 512 * 256 + (size_t)(c & 127) * 2)
                           : ((size_t)c * 2);
  float s = 0.f, q = 0.f;
  for (int i = 0; i < nl; ++i) {
    float2 v = *(const float2*)(p + base + (size_t)(t + i*256) * 256);
    s += v.x; q += v.y;
  }
  #pragma unroll
  for (int m = 1; m < 64; m <<= 1) { s += __shfl_xor(s, m); q += __shfl_xor(q, m); }
  __shared__ float2 red[4];
  if ((t & 63) == 0) red[t >> 6] = make_float2(s, q);
  __syncthreads();
  if (t == 0) {
    float ss = red[0].x + red[1].x + red[2].x + red[3].x;
    float qq = red[0].y + red[1].y + red[2].y + red[3].y;
    float mu  = ss * (1.f/65536.f);
    float var = qq * (1.f/65536.f) - mu*mu;
    float a = g[c] * rsqrtf(var + 1e-5f);
    scale[c] = a; shift[c] = be[c] - mu*a;
  }
}

// ---------------- K4: GEMM2 MFMA, register-staged period-3, BN0+ReLU on B ----------------
// grid (32,16): 4 waves (2x2), wave tile 64x64, K=8 steps.
__global__ __launch_bounds__(256) void gemm2_mfma(
    const u16* __restrict__ y0T, const u16* __restrict__ w1b,
    const float* __restrict__ b1p,
    const float* __restrict__ scale0, const float* __restrict__ shift0,
    float* __restrict__ out, float* __restrict__ p1)
{
  __shared__ float a0s[CM_], bb0s[CM_];
  __shared__ float ps[4][64][2];
  int t = threadIdx.x;
  a0s[t] = scale0[t]; bb0s[t] = shift0[t];
  __syncthreads();
  int wave = t >> 6, lane = t & 63;
  int col = lane & 15, quad = lane >> 4;
  int wm = wave >> 1, wn = wave & 1;
  int b = blockIdx.y;
  int mtb = wm*4;
  int ntb = blockIdx.x*8 + wn*4;

  const u16* ap = w1b + lane*8;
  const u16* bp = y0T + ((size_t)(b*256 + ntb)*8)*512 + lane*8;

  floatx4 acc[4][4] = {};
  bf16x8 aA[4], aB[4], aC[4];
  U128 rA[4], rB[4], rC[4];

#define G2_LDA(BUF, KT) { _Pragma("unroll") for (int i = 0; i < 4; ++i) \
    BUF[i] = ldfrag(ap + (size_t)((mtb+i)*8 + (KT))*512); }
#define G2_LDB(BUF, KT) { _Pragma("unroll") for (int i = 0; i < 4; ++i) \
    BUF[i].u = *(const uint4*)(bp + (size_t)(i*8 + (KT))*512); }
#define G2_BNMM(A_, R_, KT) { \
    int c0 = (KT)*32 + quad*8; \
    float av[8], bv[8]; \
    *(float4*)&av[0] = *(const float4*)&a0s[c0];  *(float4*)&av[4] = *(const float4*)&a0s[c0+4]; \
    *(float4*)&bv[0] = *(const float4*)&bb0s[c0]; *(float4*)&bv[4] = *(const float4*)&bb0s[c0+4]; \
    bf16x8 bfv[4]; \
    _Pragma("unroll") for (int j = 0; j < 4; ++j) { \
      u16 h8[8]; \
      _Pragma("unroll") for (int e = 0; e < 8; ++e) \
        h8[e] = f2bf(fmaxf(fmaf(bf2f(R_[j].s[e]), av[e], bv[e]), 0.f)); \
      U128 x_; x_.u = pack8(h8); bfv[j] = x_.v; } \
    _Pragma("unroll") for (int mt = 0; mt < 4; ++mt) \
    _Pragma("unroll") for (int nt = 0; nt < 4; ++nt) \
      acc[mt][nt] = __builtin_amdgcn_mfma_f32_16x16x32_bf16(A_[mt], bfv[nt], acc[mt][nt], 0, 0, 0); }

  G2_LDA(aA,0);  G2_LDB(rA,0);
  G2_LDA(aB,1);  G2_LDB(rB,1);
  G2_LDA(aC,2);  G2_LDB(rC,2);
  G2_BNMM(aA,rA,0);  G2_LDA(aA,3);  G2_LDB(rA,3);
  G2_BNMM(aB,rB,1);  G2_LDA(aB,4);  G2_LDB(rB,4);
  G2_BNMM(aC,rC,2);  G2_LDA(aC,5);  G2_LDB(rC,5);
  G2_BNMM(aA,rA,3);  G2_LDA(aA,6);  G2_LDB(rA,6);
  G2_BNMM(aB,rB,4);  G2_LDA(aB,7);  G2_LDB(rB,7);
  G2_BNMM(aC,rC,5);
  G2_BNMM(aA,rA,6);
  G2_BNMM(aB,rB,7);

  int m0 = wm*64;
  int n0 = blockIdx.x*128 + wn*64;
  #pragma unroll
  for (int mt = 0; mt < 4; ++mt) {
    float4 bias4 = *(const float4*)(b1p + m0 + mt*16 + quad*4);
    float bia[4] = {bias4.x, bias4.y, bias4.z, bias4.w};
    float s[4] = {}, q[4] = {};
    #pragma unroll
    for (int nt = 0; nt < 4; ++nt) {
      int n = n0 + nt*16 + col;
      #pragma unroll
      for (int r = 0; r < 4; ++r) {
        float v = acc[mt][nt][r] + bia[r];
        out[((size_t)b*CO_ + m0 + mt*16 + quad*4 + r)*N1_ + n] = v;
        s[r] += v; q[r] += v*v;
      }
    }
    #pragma unroll
    for (int r = 0; r < 4; ++r) {
      float ss = s[r], qq = q[r];
      #pragma unroll
      for (int msk = 1; msk < 16; msk <<= 1) { ss += __shfl_xor(ss, msk); qq += __shfl_xor(qq, msk); }
      if (col == 0) {
        ps[wave][mt*16 + quad*4 + r][0] = ss;
        ps[wave][mt*16 + quad*4 + r][1] = qq;
      }
    }
  }
  __syncthreads();
  {
    int c = t >> 1, k = t & 1;
    int wbase = (c >> 6) * 2, ch = c & 63;
    float v = ps[wbase][ch][k] + ps[wbase+1][ch][k];
    size_t l = (size_t)blockIdx.y*32 + blockIdx.x;
    p1[l*256 + t] = v;
  }
}

// ---------------- K5: BN1 + ReLU in place on d_out ----------------
__global__ __launch_bounds__(256) void bnrelu_kernel(
    float* __restrict__ out, const float* __restrict__ scale1, const float* __restrict__ shift1)
{
  int idx = blockIdx.x * 256 + threadIdx.x;   // float4 index
  int c = (idx >> 10) & (CO_ - 1);
  float a = scale1[c];
  float bb = shift1[c];
  float4 v = ((const float4*)out)[idx];
  v.x = fmaxf(fmaf(v.x, a, bb), 0.f);
  v.y = fmaxf(fmaf(v.y, a, bb), 0.f);
  v.z = fmaxf(fmaf(v.z, a, bb), 0.f);
  v.w = fmaxf(fmaf(v.w, a, bb), 0.f);
  ((float4*)out)[idx] = v;
}

extern "C" void kernel_launch(void* const* d_in, const int* in_sizes, int n_in,
                              void* d_out, int out_size, void* d_ws, size_t ws_size,
                              hipStream_t stream)
{
  const float* xyz1  = (const float*)d_in[0];
  const float* xyz2  = (const float*)d_in[1];
  const float* feat1 = (const float*)d_in[2];
  const float* feat2 = (const float*)d_in[3];
  const float* w0    = (const float*)d_in[4];
  const float* b0    = (const float*)d_in[5];
  const float* g0    = (const float*)d_in[6];
  const float* be0   = (const float*)d_in[7];
  const float* w1    = (const float*)d_in[8];
  const float* b1    = (const float*)d_in[9];
  const float* g1    = (const float*)d_in[10];
  const float* be1   = (const float*)d_in[11];
  float* out = (float*)d_out;
  char* ws = (char*)d_ws;

  // workspace layout (bytes). knn_pd/pi live in the y0T region after feat2Tb
  // (f1-transpose writes xcatT concurrently with knn in K1); both consumed by
  // interp before gemm1 writes y0T. pd/pi now 2 chunks x 3 = 1.57 MB each.
  u16*   xcatT   = (u16*)ws;                                   // 50331648
  float* p1      = (float*)ws;                                 // 524288 (alias xcatT; gemm2 writes after gemm1 consumed xcatT)
  u16*   y0T     = (u16*)(ws + 50331648);                      // 33554432
  u16*   feat2Tb = (u16*)(ws + 50331648);                      // 8388608 (alias y0T head)
  float* knn_pd  = (float*)(ws + 58720256);                    // 1572864 (alias y0T mid)
  int*   knn_pi  = (int*)(ws + 65011712);                      // 1572864 (alias y0T mid)
  u16*   w0b     = (u16*)(ws + 83886080);                      // 196608
  u16*   w1b     = (u16*)(ws + 84082688);                      // 65536
  float* p0      = (float*)(ws + 85721088);                    // 1048576
  float* scale0  = (float*)(ws + 87293952);                    // 256
  float* shift0  = scale0 + 256;
  float* scale1  = scale0 + 512;
  float* shift1  = scale0 + 640;

  mega_kernel  <<<1920,           256, 0, stream>>>(xyz1, xyz2, knn_pd, knn_pi, w0, w1,
                                                    w0b, w1b, feat2, feat2Tb, feat1, xcatT);
  interp_kernel<<<dim3(64,16),    256, 0, stream>>>(feat2Tb, knn_pd, knn_pi, xcatT);
  gemm1_mfma   <<<dim3(32,16,2),  256, 0, stream>>>(xcatT, w0b, b0, y0T, p0);
  stats_kernel <<<256,            256, 0, stream>>>(p0, g0, be0, scale0, shift0, 1, 2);
  gemm2_mfma   <<<dim3(32,16),    256, 0, stream>>>(y0T, w1b, b1, scale0, shift0, out, p1);
  stats_kernel <<<128,            256, 0, stream>>>(p1, g1, be1, scale1, shift1, 0, 2);
  bnrelu_kernel<<<8192,           256, 0, stream>>>(out, scale1, shift1);
}